// Round 2
// baseline (341.659 us; speedup 1.0000x reference)
//
#include <hip/hip_runtime.h>
#include <cstdint>
#include <cstddef>

// Problem constants (B=8192, P=8192, F=256; SIGMA=1 -> denom = 2)
#define B_ROWS 8192
#define P_ROWS 8192
#define FDIM   256

// Block geometry: each block owns a 128-row M-band x 1024-col N-strip,
// processed as 16 tiles of 64 cols. K=256 is held ENTIRELY in registers
// for A (per wave: 32 rows x 256 K = 64 VGPR) -> no A staging, no K-loop
// barriers. B is double-buffered in LDS (2 x 32 KiB), one barrier per tile,
// counted vmcnt (never vmcnt(0) in the loop).
#define BAND    128
#define STRIP   1024
#define TILE    64
#define NTILES  (STRIP / TILE)     // 16
#define NBANDS  (B_ROWS / BAND)    // 64
#define NSTRIPS (P_ROWS / STRIP)   // 8

typedef __bf16  bf16x8  __attribute__((ext_vector_type(8)));
typedef float   floatx4 __attribute__((ext_vector_type(4)));

// round-to-nearest-even fp32 -> bf16 (inputs are finite Gaussians, no NaN path)
__device__ __forceinline__ unsigned short f2bf(float f) {
  unsigned int u = __float_as_uint(f);
  u += 0x7fffu + ((u >> 16) & 1u);
  return (unsigned short)(u >> 16);
}

// async global->LDS, 16B per lane. LDS dest is wave-uniform base + lane*16.
__device__ __forceinline__ void async16(const void* g, void* l) {
  __builtin_amdgcn_global_load_lds(
      (const __attribute__((address_space(1))) void*)g,
      (__attribute__((address_space(3))) void*)l,
      16, 0, 0);
}

// ---------------------------------------------------------------------------
// Pre-pass: convert x / prototypes to bf16 planes in ws, compute fp32 row
// norms. One wave per row (64 lanes x float4 = 256 elems).
// ---------------------------------------------------------------------------
__global__ void __launch_bounds__(64) prep_kernel(
    const float* __restrict__ x, const float* __restrict__ p,
    unsigned short* __restrict__ xbf, unsigned short* __restrict__ pbf,
    float* __restrict__ x2, float* __restrict__ p2) {
  const int row  = blockIdx.x;
  const int lane = threadIdx.x;

  const float* src;
  unsigned short* dst;
  float* nrm;
  int r;
  if (row < B_ROWS) { src = x; dst = xbf; nrm = x2; r = row; }
  else              { src = p; dst = pbf; nrm = p2; r = row - B_ROWS; }

  const float4 v = *reinterpret_cast<const float4*>(src + (size_t)r * FDIM + lane * 4);
  float s = v.x * v.x + v.y * v.y + v.z * v.z + v.w * v.w;
  #pragma unroll
  for (int o = 32; o > 0; o >>= 1) s += __shfl_down(s, o);
  if (lane == 0) nrm[r] = s;

  ushort4 pk;
  pk.x = f2bf(v.x); pk.y = f2bf(v.y); pk.z = f2bf(v.z); pk.w = f2bf(v.w);
  *reinterpret_cast<ushort4*>(dst + (size_t)r * FDIM + lane * 4) = pk;
}

// ---------------------------------------------------------------------------
// Main kernel. 4 waves/block; wave w owns rows M0 + w*32 + {lm, lm+16}.
//
// A fragments: af[i][kw] = 16B of row (M0+w*32+i*16+lm), K-bytes
// [kw*64 + q*16, +16) -- the exact per-lane MFMA A layout, loaded straight
// from global (L3-resident) once per block.
//
// B LDS layout per 64-proto tile: row r (512 B = 32 chunks of 16B); chunk
// slot c holds GLOBAL K-chunk (c&24)|((c^r)&7)  [XOR swizzle -> ds_read_b128
// conflict-free], and row r holds prototype 4*(r&15)+(r>>4) [permute ->
// lane lm owns 4 contiguous output cols -> float4 stores, float4 p2 load].
// Both permutations are applied on the *global* source address; LDS dest of
// global_load_lds stays strictly lane-ordered.
//
// Sync: ONE s_barrier per tile. Staging loads for tile t+1 are issued before
// tile t's compute; at tile end `s_waitcnt vmcnt(8)` retires them while
// leaving the 8 newest ops (this tile's nt stores) in flight.
// ---------------------------------------------------------------------------
__global__ void __launch_bounds__(256, 2) gauss_kernel(
    const unsigned short* __restrict__ xbf, const unsigned short* __restrict__ pbf,
    const float* __restrict__ x2, const float* __restrict__ p2,
    float* __restrict__ out) {
  __shared__ __align__(16) unsigned short lds_b[2][TILE * FDIM];  // 2 x 32 KiB

  const int t    = threadIdx.x;
  const int lane = t & 63;
  const int w    = t >> 6;        // wave 0..3
  const int lm   = lane & 15;
  const int q    = lane >> 4;     // 0..3
  const int s3   = lm & 7;        // low-3 row bits for the XOR swizzle

  const int band  = blockIdx.x & (NBANDS - 1);
  const int strip = blockIdx.x >> 6;          // 0..7
  const int M0  = band * BAND;
  const int N0s = strip * STRIP;

  // ---- A fragments in registers (64 VGPR) + x2 rows ----
  const int rowA = M0 + w * 32 + lm;
  bf16x8 af[2][8];
  #pragma unroll
  for (int i = 0; i < 2; ++i)
    #pragma unroll
    for (int kw = 0; kw < 8; ++kw)
      af[i][kw] = *(const bf16x8*)&xbf[(size_t)(rowA + i * 16) * FDIM + kw * 32 + q * 8];

  floatx4 x2v[2];
  #pragma unroll
  for (int i = 0; i < 2; ++i)
    x2v[i] = *(const floatx4*)&x2[M0 + w * 32 + i * 16 + q * 4];

  // ---- B staging: 2048 chunks/tile, 8 per thread ----
  unsigned int bOff[8];    // byte offset into pbf for tile 0
  unsigned int ldsOff[8];  // byte offset inside a slot (lane-ordered)
  #pragma unroll
  for (int I = 0; I < 8; ++I) {
    const int L = I * 256 + w * 64 + lane;       // 0..2047
    const int r = L >> 5;                        // LDS proto-row 0..63
    const int c = L & 31;                        // LDS chunk slot
    const int g = (c & 24) | ((c ^ r) & 7);      // global K-chunk for slot c
    const int pl = 4 * (r & 15) + (r >> 4);      // permuted proto-in-tile
    bOff[I]   = (unsigned int)((((N0s + pl) * FDIM) + g * 8) * 2);
    ldsOff[I] = (unsigned int)((I * 256 + w * 64) * 16);
  }
  const char* pbfB = (const char*)pbf;

  // ---- output byte offsets (col part advances 256 B per tile) ----
  unsigned int oOff[2][4];
  #pragma unroll
  for (int i = 0; i < 2; ++i)
    #pragma unroll
    for (int v = 0; v < 4; ++v)
      oOff[i][v] = (unsigned int)(((M0 + w * 32 + i * 16 + q * 4 + v) * (size_t)P_ROWS
                                   + (N0s + 4 * lm)) * 4);

  // prologue: stage tile 0 into slot 0, drain everything once
  #pragma unroll
  for (int I = 0; I < 8; ++I)
    async16(pbfB + bOff[I], (char*)&lds_b[0][0] + ldsOff[I]);
  asm volatile("s_waitcnt vmcnt(0)" ::: "memory");
  __builtin_amdgcn_s_barrier();

  for (int tt = 0; tt < NTILES; ++tt) {
    const int cur = tt & 1;
    const floatx4 p2r = *(const floatx4*)&p2[N0s + tt * TILE + 4 * lm];

    if (tt < NTILES - 1) {   // prefetch next tile into the other slot
      #pragma unroll
      for (int I = 0; I < 8; ++I)
        async16(pbfB + bOff[I] + (unsigned int)((tt + 1) * (TILE * FDIM * 2)),
                (char*)&lds_b[cur ^ 1][0] + ldsOff[I]);
    }

    floatx4 acc[2][4] = {};
    const unsigned short* lb = &lds_b[cur][0];
    #pragma unroll
    for (int kw = 0; kw < 8; ++kw) {
      bf16x8 bfr[4];
      #pragma unroll
      for (int j = 0; j < 4; ++j) {
        const int cc = (kw * 4 + q) ^ s3;                  // swizzled chunk
        bfr[j] = *(const bf16x8*)&lb[(j * 16 + lm) * FDIM + cc * 8];
      }
      #pragma unroll
      for (int i = 0; i < 2; ++i)
        #pragma unroll
        for (int j = 0; j < 4; ++j)
          acc[i][j] = __builtin_amdgcn_mfma_f32_16x16x32_bf16(af[i][kw], bfr[j], acc[i][j], 0, 0, 0);
    }

    // epilogue: d2 -> exp(-sqrt(d2)/2), float4 nt stores
    #pragma unroll
    for (int i = 0; i < 2; ++i) {
      #pragma unroll
      for (int v = 0; v < 4; ++v) {
        floatx4 res;
        #pragma unroll
        for (int j = 0; j < 4; ++j) {
          float d2 = x2v[i][v] + p2r[j] - 2.0f * acc[i][j][v];
          d2 = fmaxf(d2, 0.0f);
          res[j] = __expf(-0.5f * sqrtf(d2));   // denom = 2*sigma^2 = 2
        }
        __builtin_nontemporal_store(
            res, (floatx4*)((char*)out + oOff[i][v] + (unsigned int)(tt * (TILE * 4))));
      }
    }

    if (tt < NTILES - 1) {
      // retire the 8 prefetch loads; leave this tile's 8 stores in flight
      asm volatile("s_waitcnt vmcnt(8)" ::: "memory");
      __builtin_amdgcn_s_barrier();
    }
  }
}

// ---------------------------------------------------------------------------
extern "C" void kernel_launch(void* const* d_in, const int* in_sizes, int n_in,
                              void* d_out, int out_size, void* d_ws, size_t ws_size,
                              hipStream_t stream) {
  const float* x = (const float*)d_in[0];
  const float* p = (const float*)d_in[1];
  float* out = (float*)d_out;

  // ws layout: xbf (4 MiB) | pbf (4 MiB) | x2 (32 KiB) | p2 (32 KiB)
  char* ws = (char*)d_ws;
  unsigned short* xbf = (unsigned short*)ws;
  unsigned short* pbf = (unsigned short*)(ws + (size_t)B_ROWS * FDIM * 2);
  float* x2 = (float*)(ws + (size_t)(B_ROWS + P_ROWS) * FDIM * 2);
  float* p2 = x2 + B_ROWS;

  prep_kernel<<<dim3(B_ROWS + P_ROWS), dim3(64), 0, stream>>>(x, p, xbf, pbf, x2, p2);

  gauss_kernel<<<dim3(NBANDS * NSTRIPS), dim3(256), 0, stream>>>(xbf, pbf, x2, p2, out);
}